// Round 1
// baseline (548.936 us; speedup 1.0000x reference)
//
#include <hip/hip_runtime.h>
#include <hip/hip_bf16.h>
#include <cmath>

// GATv2 encoder, 3 layers, d=64, f32.
// Pipeline per call:
//   1. build dst-CSR of the (edges + self-loops) graph: hist -> scan -> scatter
//   2. per layer: transform (xl = h@Wl+bl, xr = h@Wr+br), then one-wave-per-node
//      online-softmax edge aggregation fused with bias+ReLU+residual.

#define D 64

// ---------------- CSR build ----------------

__global__ __launch_bounds__(256) void hist_kernel(
    const int* __restrict__ ei, int* __restrict__ deg, int E, int N) {
  int eid = blockIdx.x * 256 + threadIdx.x;
  if (eid >= E + N) return;
  int d = (eid < E) ? ei[E + eid] : (eid - E);   // dst row of edge_index, or self-loop
  atomicAdd(&deg[d], 1);
}

__global__ __launch_bounds__(1024) void scan_kernel(
    const int* __restrict__ deg, int* __restrict__ rowptr,
    int* __restrict__ cursor, int N) {
  int tid = threadIdx.x;
  int chunk = (N + 1023) / 1024;
  int beg = tid * chunk;
  int end = min(N, beg + chunk);
  int sum = 0;
  for (int i = beg; i < end; ++i) sum += deg[i];
  int lane = tid & 63, w = tid >> 6;
  int v = sum;
#pragma unroll
  for (int off = 1; off < 64; off <<= 1) {
    int t = __shfl_up(v, off, 64);
    if (lane >= off) v += t;
  }
  __shared__ int wsum[16];
  __shared__ int woff[16];
  if (lane == 63) wsum[w] = v;
  __syncthreads();
  if (tid == 0) {
    int r = 0;
    for (int i = 0; i < 16; ++i) { woff[i] = r; r += wsum[i]; }
  }
  __syncthreads();
  int run = woff[w] + (v - sum);    // exclusive prefix for this thread's chunk
  for (int i = beg; i < end; ++i) {
    rowptr[i] = run;
    cursor[i] = run;
    run += deg[i];
  }
  if (end == N && beg < N) rowptr[N] = run;   // total = E + N
}

__global__ __launch_bounds__(256) void scatter_kernel(
    const int* __restrict__ ei, int* __restrict__ cursor,
    int* __restrict__ csr_src, int E, int N) {
  int eid = blockIdx.x * 256 + threadIdx.x;
  if (eid >= E + N) return;
  int s, d;
  if (eid < E) { s = ei[eid]; d = ei[E + eid]; }
  else         { s = d = eid - E; }
  int pos = atomicAdd(&cursor[d], 1);
  csr_src[pos] = s;
}

// ---------------- per-layer transform: xl = h@Wl+bl, xr = h@Wr+br ----------------
// 16 nodes per 256-thread block; each thread owns output column j (= lane),
// keeps W columns in registers, h rows broadcast from LDS.

__global__ __launch_bounds__(256) void transform_kernel(
    const float* __restrict__ h,
    const float* __restrict__ Wl, const float* __restrict__ bl,
    const float* __restrict__ Wr, const float* __restrict__ br,
    float* __restrict__ xl, float* __restrict__ xr, int N) {
  __shared__ float hs[16][D];
  int tid = threadIdx.x;
  int j = tid & 63;
  float wl[D], wr[D];
#pragma unroll
  for (int k = 0; k < D; ++k) {   // coalesced across lanes for each k
    wl[k] = Wl[k * D + j];
    wr[k] = Wr[k * D + j];
  }
  int node0 = blockIdx.x * 16;
  for (int i = tid; i < 16 * D; i += 256) {
    int n = node0 + (i >> 6);
    hs[i >> 6][i & 63] = (n < N) ? h[(size_t)n * D + (i & 63)] : 0.f;
  }
  __syncthreads();
  float blj = bl[j], brj = br[j];
  int nl = tid >> 6;
  for (int g = 0; g < 4; ++g) {
    int local = nl * 4 + g;
    int n = node0 + local;
    float al = blj, ar = brj;
#pragma unroll
    for (int k4 = 0; k4 < D / 4; ++k4) {
      float4 hv = *reinterpret_cast<const float4*>(&hs[local][k4 * 4]);
      al = fmaf(hv.x, wl[k4 * 4 + 0], al);
      ar = fmaf(hv.x, wr[k4 * 4 + 0], ar);
      al = fmaf(hv.y, wl[k4 * 4 + 1], al);
      ar = fmaf(hv.y, wr[k4 * 4 + 1], ar);
      al = fmaf(hv.z, wl[k4 * 4 + 2], al);
      ar = fmaf(hv.z, wr[k4 * 4 + 2], ar);
      al = fmaf(hv.w, wl[k4 * 4 + 3], al);
      ar = fmaf(hv.w, wr[k4 * 4 + 3], ar);
    }
    if (n < N) {
      xl[(size_t)n * D + j] = al;
      xr[(size_t)n * D + j] = ar;
    }
  }
}

// ---------------- edge aggregation: one wave per dst node, online softmax ----------------
// Fused: GATv2 score, segment softmax, weighted sum, +bias, ReLU, +residual.

__global__ __launch_bounds__(256) void edge_kernel(
    const float* __restrict__ xl, const float* __restrict__ xr,
    const float* __restrict__ h_in, const int* __restrict__ rowptr,
    const int* __restrict__ csr_src, const float* __restrict__ att,
    const float* __restrict__ bias, float* __restrict__ h_out, int N) {
  int wid = (blockIdx.x * blockDim.x + threadIdx.x) >> 6;
  int lane = threadIdx.x & 63;
  if (wid >= N) return;
  int v = wid;
  float xrv = xr[v * D + lane];
  float aj = att[lane];
  int beg = rowptr[v], end = rowptr[v + 1];
  float m = -INFINITY, s = 0.f, acc = 0.f;
  for (int tb = beg; tb < end; tb += 64) {
    int nt = min(64, end - tb);
    int us = (tb + lane < end) ? csr_src[tb + lane] : 0;  // coalesced batch of srcs
    for (int k = 0; k < nt; ++k) {
      int u = __shfl(us, k, 64);
      float xlu = xl[(size_t)u * D + lane];
      float val = xlu + xrv;
      val = (val > 0.f) ? val : 0.2f * val;    // leaky_relu, slope 0.2
      float p = val * aj;
#pragma unroll
      for (int o = 32; o > 0; o >>= 1) p += __shfl_xor(p, o, 64);  // score in all lanes
      float mn = fmaxf(m, p);
      float sc = __expf(m - mn);    // m=-inf first iter -> 0
      float w = __expf(p - mn);
      s = s * sc + w;
      acc = acc * sc + w * xlu;
      m = mn;
    }
  }
  float o = acc / s + bias[lane];
  o = fmaxf(o, 0.f);
  h_out[v * D + lane] = o + h_in[v * D + lane];
}

// ---------------- launch ----------------

extern "C" void kernel_launch(void* const* d_in, const int* in_sizes, int n_in,
                              void* d_out, int out_size, void* d_ws, size_t ws_size,
                              hipStream_t stream) {
  const float* x    = (const float*)d_in[0];
  const int*   ei   = (const int*)d_in[1];
  const float* Wl   = (const float*)d_in[2];
  const float* bl   = (const float*)d_in[3];
  const float* Wr   = (const float*)d_in[4];
  const float* br   = (const float*)d_in[5];
  const float* att  = (const float*)d_in[6];
  const float* bias = (const float*)d_in[7];

  int N = in_sizes[0] / D;
  int E = in_sizes[1] / 2;
  int L = in_sizes[2] / (D * D);
  int EP = E + N;

  float* xl = (float*)d_ws;
  float* xr = xl + (size_t)N * D;
  float* hA = xr + (size_t)N * D;
  float* hB = hA + (size_t)N * D;
  int* deg     = (int*)(hB + (size_t)N * D);
  int* cursor  = deg + N;
  int* rowptr  = cursor + N;
  int* csr_src = rowptr + (N + 1);

  // CSR build (graph is layer-invariant: build once per call)
  hipMemsetAsync(deg, 0, (size_t)N * sizeof(int), stream);
  hist_kernel<<<(EP + 255) / 256, 256, 0, stream>>>(ei, deg, E, N);
  scan_kernel<<<1, 1024, 0, stream>>>(deg, rowptr, cursor, N);
  scatter_kernel<<<(EP + 255) / 256, 256, 0, stream>>>(ei, cursor, csr_src, E, N);

  const float* h_in = x;
  for (int l = 0; l < L; ++l) {
    float* h_out = (l == L - 1) ? (float*)d_out : ((l % 2 == 0) ? hA : hB);
    transform_kernel<<<(N + 15) / 16, 256, 0, stream>>>(
        h_in, Wl + (size_t)l * D * D, bl + (size_t)l * D,
        Wr + (size_t)l * D * D, br + (size_t)l * D, xl, xr, N);
    edge_kernel<<<((N + 3) / 4), 256, 0, stream>>>(
        xl, xr, h_in, rowptr, csr_src, att + (size_t)l * D,
        bias + (size_t)l * D, h_out, N);
    h_in = h_out;
  }
}

// Round 2
// 315.629 us; speedup vs baseline: 1.7392x; 1.7392x over previous
//
#include <hip/hip_runtime.h>
#include <hip/hip_bf16.h>
#include <cmath>

// GATv2 encoder, 3 layers, d=64, f32.
// Pipeline per call:
//   1. build dst-CSR: hist -> hierarchical scan (3 small kernels) -> scatter
//   2. per layer: transform (xl = h@Wl+bl, xr = h@Wr+br), then one-wave-per-node
//      edge aggregation (4 edges x 16 lanes, online softmax) fused with
//      bias+ReLU+residual.

#define D 64
#define SCAN_TILE 1024

// ---------------- CSR build ----------------

__global__ __launch_bounds__(256) void hist_kernel(
    const int* __restrict__ ei, int* __restrict__ deg, int E, int N) {
  int eid = blockIdx.x * 256 + threadIdx.x;
  if (eid >= E + N) return;
  int d = (eid < E) ? ei[E + eid] : (eid - E);   // dst row of edge_index, or self-loop
  atomicAdd(&deg[d], 1);
}

// tile-sum of deg
__global__ __launch_bounds__(256) void scan_partial_kernel(
    const int* __restrict__ deg, int* __restrict__ partial, int N) {
  int b = blockIdx.x;
  int tid = threadIdx.x;
  int beg = b * SCAN_TILE;
  int end = min(N, beg + SCAN_TILE);
  int sum = 0;
  for (int i = beg + tid; i < end; i += 256) sum += deg[i];
#pragma unroll
  for (int o = 1; o < 64; o <<= 1) sum += __shfl_xor(sum, o, 64);
  __shared__ int ws[4];
  if ((tid & 63) == 0) ws[tid >> 6] = sum;
  __syncthreads();
  if (tid == 0) partial[b] = ws[0] + ws[1] + ws[2] + ws[3];
}

// exclusive scan of tile sums (nb <= 64: one wave)
__global__ __launch_bounds__(64) void scan_offsets_kernel(
    int* __restrict__ partial, int nb) {
  int tid = threadIdx.x;
  int v = (tid < nb) ? partial[tid] : 0;
  int orig = v;
#pragma unroll
  for (int o = 1; o < 64; o <<= 1) {
    int t = __shfl_up(v, o, 64);
    if (tid >= o) v += t;
  }
  if (tid < nb) partial[tid] = v - orig;
}

// per-tile scan + write rowptr/cursor
__global__ __launch_bounds__(256) void scan_apply_kernel(
    const int* __restrict__ deg, const int* __restrict__ partial,
    int* __restrict__ rowptr, int* __restrict__ cursor, int N) {
  int b = blockIdx.x;
  int tid = threadIdx.x;
  int i0 = b * SCAN_TILE + tid * 4;
  int d0 = (i0     < N) ? deg[i0]     : 0;
  int d1 = (i0 + 1 < N) ? deg[i0 + 1] : 0;
  int d2 = (i0 + 2 < N) ? deg[i0 + 2] : 0;
  int d3 = (i0 + 3 < N) ? deg[i0 + 3] : 0;
  int tsum = d0 + d1 + d2 + d3;
  int lane = tid & 63, w = tid >> 6;
  int v = tsum;
#pragma unroll
  for (int o = 1; o < 64; o <<= 1) {
    int t = __shfl_up(v, o, 64);
    if (lane >= o) v += t;
  }
  __shared__ int wsum[4], woff[4];
  if (lane == 63) wsum[w] = v;
  __syncthreads();
  if (tid == 0) { int r = 0; for (int i = 0; i < 4; ++i) { woff[i] = r; r += wsum[i]; } }
  __syncthreads();
  int off = partial[b] + woff[w] + v - tsum;   // exclusive prefix for i0
  if (i0     < N) { rowptr[i0]     = off; cursor[i0]     = off; }
  off += d0;
  if (i0 + 1 < N) { rowptr[i0 + 1] = off; cursor[i0 + 1] = off; }
  off += d1;
  if (i0 + 2 < N) { rowptr[i0 + 2] = off; cursor[i0 + 2] = off; }
  off += d2;
  if (i0 + 3 < N) { rowptr[i0 + 3] = off; cursor[i0 + 3] = off; }
  off += d3;
  if (i0 < N && i0 + 4 >= N) rowptr[N] = off;  // total = E + N
}

__global__ __launch_bounds__(256) void scatter_kernel(
    const int* __restrict__ ei, int* __restrict__ cursor,
    int* __restrict__ csr_src, int E, int N) {
  int eid = blockIdx.x * 256 + threadIdx.x;
  if (eid >= E + N) return;
  int s, d;
  if (eid < E) { s = ei[eid]; d = ei[E + eid]; }
  else         { s = d = eid - E; }
  int pos = atomicAdd(&cursor[d], 1);
  csr_src[pos] = s;
}

// ---------------- per-layer transform: xl = h@Wl+bl, xr = h@Wr+br ----------------

__global__ __launch_bounds__(256) void transform_kernel(
    const float* __restrict__ h,
    const float* __restrict__ Wl, const float* __restrict__ bl,
    const float* __restrict__ Wr, const float* __restrict__ br,
    float* __restrict__ xl, float* __restrict__ xr, int N) {
  __shared__ float hs[16][D];
  int tid = threadIdx.x;
  int j = tid & 63;
  float wl[D], wr[D];
#pragma unroll
  for (int k = 0; k < D; ++k) {   // coalesced across lanes for each k
    wl[k] = Wl[k * D + j];
    wr[k] = Wr[k * D + j];
  }
  int node0 = blockIdx.x * 16;
  for (int i = tid; i < 16 * D; i += 256) {
    int n = node0 + (i >> 6);
    hs[i >> 6][i & 63] = (n < N) ? h[(size_t)n * D + (i & 63)] : 0.f;
  }
  __syncthreads();
  float blj = bl[j], brj = br[j];
  int nl = tid >> 6;
  for (int g = 0; g < 4; ++g) {
    int local = nl * 4 + g;
    int n = node0 + local;
    float al = blj, ar = brj;
#pragma unroll
    for (int k4 = 0; k4 < D / 4; ++k4) {
      float4 hv = *reinterpret_cast<const float4*>(&hs[local][k4 * 4]);
      al = fmaf(hv.x, wl[k4 * 4 + 0], al);
      ar = fmaf(hv.x, wr[k4 * 4 + 0], ar);
      al = fmaf(hv.y, wl[k4 * 4 + 1], al);
      ar = fmaf(hv.y, wr[k4 * 4 + 1], ar);
      al = fmaf(hv.z, wl[k4 * 4 + 2], al);
      ar = fmaf(hv.z, wr[k4 * 4 + 2], ar);
      al = fmaf(hv.w, wl[k4 * 4 + 3], al);
      ar = fmaf(hv.w, wr[k4 * 4 + 3], ar);
    }
    if (n < N) {
      xl[(size_t)n * D + j] = al;
      xr[(size_t)n * D + j] = ar;
    }
  }
}

// ---------------- edge aggregation ----------------
// One wave per dst node. 16 lanes per edge (4 f32 features each), 4 edges
// processed concurrently. Online softmax state (m, s) kept wave-uniform;
// accumulator is float4/lane, partial per edge-group, reduced at the end.
// Fused: GATv2 score, segment softmax, weighted sum, +bias, ReLU, +residual.

__global__ __launch_bounds__(256) void edge_kernel(
    const float* __restrict__ xl, const float* __restrict__ xr,
    const float* __restrict__ h_in, const int* __restrict__ rowptr,
    const int* __restrict__ csr_src, const float* __restrict__ att,
    const float* __restrict__ bias, float* __restrict__ h_out, int N) {
  int wid = (blockIdx.x * blockDim.x + threadIdx.x) >> 6;
  if (wid >= N) return;
  int lane = threadIdx.x & 63;
  int g = lane >> 4;          // edge slot 0..3 within a batch
  int l16 = lane & 15;        // feature-quad index
  int v = wid;
  float4 xr4 = *reinterpret_cast<const float4*>(&xr[(size_t)v * D + l16 * 4]);
  float4 at4 = *reinterpret_cast<const float4*>(&att[l16 * 4]);
  int beg = rowptr[v], end = rowptr[v + 1];
  float m = -INFINITY, s = 0.f;
  float ax = 0.f, ay = 0.f, az = 0.f, aw = 0.f;
  for (int tb = beg; tb < end; tb += 64) {
    int us = (tb + lane < end) ? csr_src[tb + lane] : 0;  // coalesced src batch
    int nb = min(64, end - tb);
    for (int b4 = 0; b4 < nb; b4 += 4) {
      int u = __shfl(us, b4 + g, 64);
      bool act = (b4 + g < nb);
      float4 xu = make_float4(0.f, 0.f, 0.f, 0.f);
      if (act) xu = *reinterpret_cast<const float4*>(&xl[(size_t)u * D + l16 * 4]);
      float tx = xu.x + xr4.x, ty = xu.y + xr4.y;
      float tz = xu.z + xr4.z, tw = xu.w + xr4.w;
      tx = (tx > 0.f) ? tx : 0.2f * tx;     // leaky_relu, slope 0.2
      ty = (ty > 0.f) ? ty : 0.2f * ty;
      tz = (tz > 0.f) ? tz : 0.2f * tz;
      tw = (tw > 0.f) ? tw : 0.2f * tw;
      float p = tx * at4.x + ty * at4.y + tz * at4.z + tw * at4.w;
      p += __shfl_xor(p, 1, 64);            // reduce over the 16-lane group
      p += __shfl_xor(p, 2, 64);
      p += __shfl_xor(p, 4, 64);
      p += __shfl_xor(p, 8, 64);
      p = act ? p : -INFINITY;
      float pm = fmaxf(p, __shfl_xor(p, 16, 64));   // max over the 4 groups
      pm = fmaxf(pm, __shfl_xor(pm, 32, 64));
      float mn = fmaxf(m, pm);
      float sc = __expf(m - mn);            // first iter: exp(-inf) = 0
      float w  = __expf(p - mn);            // inactive: 0
      float sw = w + __shfl_xor(w, 16, 64); // sum of the 4 edge weights
      sw += __shfl_xor(sw, 32, 64);
      s = s * sc + sw;
      ax = ax * sc + w * xu.x;
      ay = ay * sc + w * xu.y;
      az = az * sc + w * xu.z;
      aw = aw * sc + w * xu.w;
      m = mn;
    }
  }
  // combine per-group partial accumulators (same feature slots, different edges)
  ax += __shfl_xor(ax, 16, 64); ax += __shfl_xor(ax, 32, 64);
  ay += __shfl_xor(ay, 16, 64); ay += __shfl_xor(ay, 32, 64);
  az += __shfl_xor(az, 16, 64); az += __shfl_xor(az, 32, 64);
  aw += __shfl_xor(aw, 16, 64); aw += __shfl_xor(aw, 32, 64);
  if (g == 0) {
    float4 b4v = *reinterpret_cast<const float4*>(&bias[l16 * 4]);
    float4 hv  = *reinterpret_cast<const float4*>(&h_in[(size_t)v * D + l16 * 4]);
    float inv = 1.f / s;
    float4 o;
    o.x = fmaxf(ax * inv + b4v.x, 0.f) + hv.x;
    o.y = fmaxf(ay * inv + b4v.y, 0.f) + hv.y;
    o.z = fmaxf(az * inv + b4v.z, 0.f) + hv.z;
    o.w = fmaxf(aw * inv + b4v.w, 0.f) + hv.w;
    *reinterpret_cast<float4*>(&h_out[(size_t)v * D + l16 * 4]) = o;
  }
}

// ---------------- launch ----------------

extern "C" void kernel_launch(void* const* d_in, const int* in_sizes, int n_in,
                              void* d_out, int out_size, void* d_ws, size_t ws_size,
                              hipStream_t stream) {
  const float* x    = (const float*)d_in[0];
  const int*   ei   = (const int*)d_in[1];
  const float* Wl   = (const float*)d_in[2];
  const float* bl   = (const float*)d_in[3];
  const float* Wr   = (const float*)d_in[4];
  const float* br   = (const float*)d_in[5];
  const float* att  = (const float*)d_in[6];
  const float* bias = (const float*)d_in[7];

  int N = in_sizes[0] / D;
  int E = in_sizes[1] / 2;
  int L = in_sizes[2] / (D * D);
  int EP = E + N;
  int nb = (N + SCAN_TILE - 1) / SCAN_TILE;

  float* xl = (float*)d_ws;
  float* xr = xl + (size_t)N * D;
  float* hA = xr + (size_t)N * D;
  float* hB = hA + (size_t)N * D;
  int* deg     = (int*)(hB + (size_t)N * D);
  int* cursor  = deg + N;
  int* rowptr  = cursor + N;
  int* csr_src = rowptr + (N + 1);
  int* partial = csr_src + EP;

  // CSR build (graph is layer-invariant: build once per call)
  hipMemsetAsync(deg, 0, (size_t)N * sizeof(int), stream);
  hist_kernel<<<(EP + 255) / 256, 256, 0, stream>>>(ei, deg, E, N);
  scan_partial_kernel<<<nb, 256, 0, stream>>>(deg, partial, N);
  scan_offsets_kernel<<<1, 64, 0, stream>>>(partial, nb);
  scan_apply_kernel<<<nb, 256, 0, stream>>>(deg, partial, rowptr, cursor, N);
  scatter_kernel<<<(EP + 255) / 256, 256, 0, stream>>>(ei, cursor, csr_src, E, N);

  const float* h_in = x;
  for (int l = 0; l < L; ++l) {
    float* h_out = (l == L - 1) ? (float*)d_out : ((l % 2 == 0) ? hA : hB);
    transform_kernel<<<(N + 15) / 16, 256, 0, stream>>>(
        h_in, Wl + (size_t)l * D * D, bl + (size_t)l * D,
        Wr + (size_t)l * D * D, br + (size_t)l * D, xl, xr, N);
    edge_kernel<<<((N + 3) / 4), 256, 0, stream>>>(
        xl, xr, h_in, rowptr, csr_src, att + (size_t)l * D,
        bias + (size_t)l * D, h_out, N);
    h_in = h_out;
  }
}